// Round 8
// baseline (5994.508 us; speedup 1.0000x reference)
//
#include <hip/hip_runtime.h>

#define D 100
#define TT 2048
#define BB 128
#define CHUNK 32
#define NCHUNK (TT / CHUNK)   /* 64 */
#define NTHR 896              /* 14 waves: 0=consumer, 1..12=producers, 13=stager */
#define WSTR 104              /* W_lds row stride: 416B, 16B-aligned b128 reads */

static __device__ __constant__ float KLO = 2.8853900817779268f;   // 2*log2(e)
static __device__ __constant__ float MKF = -2.8853900817779268f;  // -2*log2(e)

// q += dpp_shuffle(q); ctrl must be an immediate
#define DPP_ADD(q, ctrl)                                                      \
  q += __int_as_float(__builtin_amdgcn_update_dpp(                            \
      0, __float_as_int(q), ctrl, 0xF, 0xF, true))

// ---------------------------------------------------------------------------
// K1: ab2m[j] = -log2(e) * (pos_table[j] . w_ap + b0)
// ---------------------------------------------------------------------------
__global__ void k1_pos(const float* __restrict__ pos, const float* __restrict__ wap,
                       const float* __restrict__ bb, float* __restrict__ ab2m) {
  int j = blockIdx.x * blockDim.x + threadIdx.x;
  if (j < TT) {
    float a = 0.f;
    #pragma unroll 4
    for (int e = 0; e < D; ++e) a = fmaf(pos[j * D + e], wap[e], a);
    ab2m[j] = -1.4426950408889634f * (a + bb[0]);
  }
}

// ---------------------------------------------------------------------------
// Fused scan, one block (14 waves) per batch row.
//   wave 0      : sequential chain (all steady-state reads from LDS)
//   waves 1..12 : g partial dots from W_lds (LDS-resident w_r) x hstage
//   wave 13     : stages h chunk cc+2 into hstage[(cc+2)%3]
//
// R1-R7 lesson: the allocator will NOT keep >50-float per-lane arrays in
// VGPRs here (budget pinned at 64-128; R7's mixed global/LDS wr init killed
// rematerialization -> real scratch spills -> 1.8 GB HBM). So w_r lives in
// LDS; producers keep only acc[11] + a float4 -> ~35 live VGPRs, no spills.
// ---------------------------------------------------------------------------
__global__ void __launch_bounds__(NTHR)
sp_scan(const float* __restrict__ h, const float* __restrict__ dv,
        const float* __restrict__ w_c, const float* __restrict__ w_s,
        const float* __restrict__ w_r, const float* __restrict__ ab2m,
        float* __restrict__ out) {
  __shared__ __align__(16) float W_lds[128][WSTR];       // 52 KiB (w_r + crow + zero rows)
  __shared__ __align__(16) float gbuf[2][CHUNK][256];    // 64 KiB
  __shared__ __align__(16) float hstage[3][CHUNK][104];  // 39 KiB
  const int b = blockIdx.x;
  const int tid = (int)threadIdx.x;
  const int lane = tid & 63;
  const int wvu = __builtin_amdgcn_readfirstlane(tid) >> 6;  // 0..13

  const float* hb = h + (size_t)b * TT * D;

  // ======== phase A ========================================================
  // A1: all waves cooperatively load W rows 0..99 (+zero pad cols 100..103)
  for (int r = wvu; r < D; r += 14) {
    W_lds[r][lane] = w_r[r * D + lane];
    if (lane < 36)      W_lds[r][64 + lane] = w_r[r * D + 64 + lane];
    else if (lane < 40) W_lds[r][64 + lane] = 0.f;
  }
  // A2: crow partial sums (5 parts x 20 dd, 640 threads) into gbuf scratch
  if (tid < 640) {
    float* sc = &gbuf[0][0][0];
    const int e = tid & 127;
    const int part = tid >> 7;  // 0..4
    float a1 = 0.f, a2 = 0.f;
    if (e < D) {
      const int d0 = part * 20;
      #pragma unroll 4
      for (int k = 0; k < 20; ++k) {
        const float dvv = dv[b * D + d0 + k];
        a1 = fmaf(dvv, w_s[(d0 + k) * D + e], a1);
        a2 += w_r[(d0 + k) * D + e];
      }
    }
    sc[part * 128 + e] = a1;
    sc[640 + part * 128 + e] = a2;
  }
  // A3: waves 10..12 zero W rows 101..127
  if (wvu >= 10 && wvu <= 12) {
    float* wz = &W_lds[101][0];
    for (int i = tid - 640; i < 27 * WSTR; i += 192) wz[i] = 0.f;
  }
  // A4: wave 13 stages h chunk 0 (+zero pad cols)
  if (wvu == 13) {
    for (int s = 0; s < CHUNK; ++s) {
      const float* hr = hb + (size_t)s * D;
      hstage[0][s][lane] = hr[lane];
      if (lane < 40) hstage[0][s][64 + lane] = (lane < 36) ? hr[64 + lane] : 0.f;
    }
  }
  __syncthreads();

  // ======== phase B ========================================================
  // crow reduce -> W_lds row 100 (synthetic row); stager stages chunk 1
  if (tid < 128) {
    const float* sc = &gbuf[0][0][0];
    float a1 = sc[tid] + sc[128 + tid] + sc[256 + tid] + sc[384 + tid] + sc[512 + tid];
    float a2 = sc[640 + tid] + sc[768 + tid] + sc[896 + tid] + sc[1024 + tid] + sc[1152 + tid];
    if (tid < D)            W_lds[100][tid] = w_c[tid] + a1 - a2;
    else if (tid < WSTR)    W_lds[100][tid] = 0.f;
  } else if (wvu == 13) {
    const float* hc = hb + (size_t)CHUNK * D;
    for (int s = 0; s < CHUNK; ++s) {
      const float* hr = hc + (size_t)s * D;
      hstage[1][s][lane] = hr[lane];
      if (lane < 40) hstage[1][s][64 + lane] = (lane < 36) ? hr[64 + lane] : 0.f;
    }
  }
  __syncthreads();

  // producer task decode (wave-uniform): q = 0..11
  const int q = wvu - 1;
  const int sgrp = q % 3;        // s == sgrp (mod 3)
  const int rh = (q / 3) & 1;    // row half
  const int hf = q / 6;          // element half
  const int eoff = hf * 52;
  const int row = rh * 64 + lane;
  const int col = hf * 128 + rh * 64 + lane;

  // produce g partials for one chunk from hstage[hbuf] into gw
  auto produce = [&](float (*gw)[256], int hbuf) {
    float acc[11];
    #pragma unroll
    for (int i = 0; i < 11; ++i) acc[i] = 0.f;
    const float* wrow = &W_lds[row][eoff];
    #pragma unroll
    for (int k = 0; k < 13; ++k) {
      const float4 wq = *(const float4*)(wrow + 4 * k);
      #pragma unroll
      for (int i = 0; i < 11; ++i) {
        const int s = sgrp + 3 * i;
        if (s < CHUNK) {
          const float4 hq = *(const float4*)(&hstage[hbuf][s][eoff] + 4 * k);
          acc[i] += fmaf(wq.x, hq.x, fmaf(wq.y, hq.y,
                     fmaf(wq.z, hq.z, wq.w * hq.w)));
        }
      }
    }
    #pragma unroll
    for (int i = 0; i < 11; ++i) {
      const int s = sgrp + 3 * i;
      if (s < CHUNK) gw[s][col] = acc[i];
    }
  };

  // consumer state
  float Slo = 0.f, Shi = 0.f, c = 0.f, hlp = 0.f, hhp = 0.f, pout = 0.f;
  float hlr0 = 0.f, hlr1 = 0.f, hhr0 = 0.f, hhr1 = 0.f, abrow_ = 0.f;

  // ======== phase C ========================================================
  if (wvu == 0) {
    __builtin_amdgcn_s_setprio(1);
    abrow_ = ab2m[lane & 31];
    hlr0 = hstage[0][0][lane];
    hlr1 = hstage[0][1][lane];
    if (lane < 36) { hhr0 = hstage[0][0][64 + lane]; hhr1 = hstage[0][1][64 + lane]; }
  } else if (wvu <= 12) {
    produce(gbuf[0], 0);  // chunk 0
  }
  __syncthreads();

  // ======== main loop: 64 windows =========================================
  int bufc = 0;  // cc % 3
  for (int cc = 0; cc < NCHUNK; ++cc) {
    const int bufn = (bufc == 2) ? 0 : bufc + 1;
    if (wvu == 0) {
      float (*gb)[256] = gbuf[cc & 1];
      float g0l = gb[0][lane] + gb[0][128 + lane];
      float g0h = gb[0][64 + lane] + gb[0][192 + lane];
      float g1l = gb[1][lane] + gb[1][128 + lane];
      float g1h = gb[1][64 + lane] + gb[1][192 + lane];
      const int ncc = (cc + 1 < NCHUNK) ? cc + 1 : cc;
      float abn = ab2m[ncc * CHUNK + (lane & 31)];
      const bool notlast = (cc != NCHUNK - 1);
      #pragma unroll
      for (int s = 0; s < CHUNK; ++s) {
        float hlN = 0.f, hhN = 0.f;
        if (s < CHUNK - 2) {
          const float* hr = &hstage[bufc][s + 2][0];
          hlN = hr[lane];
          if (lane < 36) hhN = hr[64 + lane];
        } else if (notlast) {
          const float* hr = &hstage[bufn][s + 2 - CHUNK][0];
          hlN = hr[lane];
          if (lane < 36) hhN = hr[64 + lane];
        }
        float g2l = 0.f, g2h = 0.f;
        if (s < CHUNK - 2) {
          g2l = gb[s + 2][lane] + gb[s + 2][128 + lane];
          g2h = gb[s + 2][64 + lane] + gb[s + 2][192 + lane];
        }
        // ---- sequential chain ----
        Slo = fmaf(hlp, c, Slo);
        Shi = fmaf(hhp, c, Shi);
        float rlo = __builtin_amdgcn_rcpf(1.f + __builtin_amdgcn_exp2f(Slo));
        float rhi = __builtin_amdgcn_rcpf(1.f + __builtin_amdgcn_exp2f(Shi));
        float qq = rlo * g0l;
        qq = fmaf(rhi, g0h, qq);
        DPP_ADD(qq, 0xB1);
        DPP_ADD(qq, 0x4E);
        DPP_ADD(qq, 0x141);
        DPP_ADD(qq, 0x140);
        const int qi = __float_as_int(qq);
        float ra = __int_as_float(__builtin_amdgcn_readlane(qi, 0)) +
                   __int_as_float(__builtin_amdgcn_readlane(qi, 16));
        float rb = __int_as_float(__builtin_amdgcn_readlane(qi, 32)) +
                   __int_as_float(__builtin_amdgcn_readlane(qi, 48));
        float R = ra + rb;
        float abv = __int_as_float(
            __builtin_amdgcn_readlane(__float_as_int(abrow_), s));
        float nz = fmaf(MKF, R, abv);
        float p = __builtin_amdgcn_rcpf(1.f + __builtin_amdgcn_exp2f(nz));
        pout = (lane == s) ? p : pout;
        c = p;
        float hl_cur = (s & 1) ? hlr1 : hlr0;
        float hh_cur = (s & 1) ? hhr1 : hhr0;
        hlp = KLO * hl_cur;
        hhp = KLO * hh_cur;
        if (s == 0) {
          if (cc == 0) { hlp = 0.f; hhp = 0.f; }  // j==0 mask
        }
        if (s & 1) { hlr1 = hlN; hhr1 = hhN; } else { hlr0 = hlN; hhr0 = hhN; }
        g0l = g1l; g0h = g1h; g1l = g2l; g1h = g2h;
      }
      if (lane < CHUNK) out[(size_t)b * TT + cc * CHUNK + lane] = pout;
      abrow_ = abn;
    } else if (wvu <= 12) {
      if (cc + 1 < NCHUNK) {
        produce(gbuf[(cc + 1) & 1], bufn);
      }
    } else {
      if (cc + 2 < NCHUNK) {
        const int bufs = (bufn == 2) ? 0 : bufn + 1;
        const float* hc = hb + (size_t)(cc + 2) * CHUNK * D;
        for (int s = 0; s < CHUNK; ++s) {
          const float* hr = hc + (size_t)s * D;
          hstage[bufs][s][lane] = hr[lane];
          if (lane < 40) hstage[bufs][s][64 + lane] = (lane < 36) ? hr[64 + lane] : 0.f;
        }
      }
    }
    __syncthreads();
    bufc = bufn;
  }
}

extern "C" void kernel_launch(void* const* d_in, const int* in_sizes, int n_in,
                              void* d_out, int out_size, void* d_ws, size_t ws_size,
                              hipStream_t stream) {
  const float* h   = (const float*)d_in[0];
  const float* dv  = (const float*)d_in[1];
  const float* w_c = (const float*)d_in[2];
  const float* w_s = (const float*)d_in[3];
  const float* w_r = (const float*)d_in[4];
  const float* pos = (const float*)d_in[5];
  const float* wap = (const float*)d_in[6];
  const float* bb  = (const float*)d_in[7];
  float* out = (float*)d_out;
  float* ab2m = (float*)d_ws;  // 2048 floats

  hipLaunchKernelGGL(k1_pos, dim3(TT / 256), dim3(256), 0, stream, pos, wap, bb, ab2m);
  hipLaunchKernelGGL(sp_scan, dim3(BB), dim3(NTHR), 0, stream,
                     h, dv, w_c, w_s, w_r, ab2m, out);
}